// Round 6
// baseline (365.208 us; speedup 1.0000x reference)
//
#include <hip/hip_runtime.h>

typedef __bf16 bf16;
typedef __attribute__((ext_vector_type(8))) __bf16 bf16x8;
typedef __attribute__((ext_vector_type(4))) float f32x4;

// Problem constants
constexpr int kS   = 2048;
constexpr int kNH  = 16;
constexpr int kNKV = 8;
constexpr int kD   = 128;
constexpr int kNqkv = 4096;   // NH*D + 2*NKV*D

// ---------------------------------------------------------------------------
// async global->LDS, 16 B per lane. LDS dest is wave-uniform base + lane*16.
// ---------------------------------------------------------------------------
__device__ __forceinline__ void async_copy16(void* lds_base_uniform, const void* g) {
  __builtin_amdgcn_global_load_lds(
      (const __attribute__((address_space(1))) void*)g,
      (__attribute__((address_space(3))) void*)lds_base_uniform, 16, 0, 0);
}

// ---------------------------------------------------------------------------
// Dtype detector: flag=1 if inputs are float32, 0 if bf16 (verified R2: f32).
// ---------------------------------------------------------------------------
__global__ void detect_dtype(const unsigned short* __restrict__ hs, int* __restrict__ flag) {
  __shared__ int cnt;
  if (threadIdx.x == 0) cnt = 0;
  __syncthreads();
  int local = 0;
  for (int i = threadIdx.x; i < 8192; i += 256) {
    int e = (hs[i] >> 7) & 0xFF;
    local += (e >= 0x85) ? 1 : 0;
  }
  atomicAdd(&cnt, local);
  __syncthreads();
  if (threadIdx.x == 0) flag[0] = (cnt > 256) ? 1 : 0;
}

__device__ __forceinline__ float ld_elem(const void* p, size_t i, int f32) {
  return f32 ? ((const float*)p)[i] : (float)((const bf16*)p)[i];
}

__device__ __forceinline__ bf16x8 load8(const void* base, size_t eoff, int f32) {
  if (f32) {
    const float* p = (const float*)base + eoff;
    f32x4 a = *(const f32x4*)p;
    f32x4 b = *(const f32x4*)(p + 4);
    bf16x8 r;
    r[0]=(bf16)a[0]; r[1]=(bf16)a[1]; r[2]=(bf16)a[2]; r[3]=(bf16)a[3];
    r[4]=(bf16)b[0]; r[5]=(bf16)b[1]; r[6]=(bf16)b[2]; r[7]=(bf16)b[3];
    return r;
  }
  return *(const bf16x8*)((const bf16*)base + eoff);
}

// ---------------------------------------------------------------------------
// hs (f32 or bf16 per flag) -> bf16, so gemm1 can use the pure async path.
// ---------------------------------------------------------------------------
__global__ void convert_hs(const void* __restrict__ hs, bf16* __restrict__ out,
                           const int* __restrict__ flagp) {
  const int f32 = flagp[0];
  const size_t i = ((size_t)blockIdx.x * 256 + threadIdx.x) * 8;
  *(bf16x8*)(out + i) = load8(hs, i, f32);
}

// ---------------------------------------------------------------------------
// Weight transpose: W (K x N) row-major -> WT (N x K) row-major, K = 2048.
// ---------------------------------------------------------------------------
__global__ void transpose_weights(const void* __restrict__ Wq, const void* __restrict__ Wk,
                                  const void* __restrict__ Wv, const void* __restrict__ Wo,
                                  bf16* __restrict__ WQKVT, bf16* __restrict__ WOT,
                                  const int* __restrict__ flagp, int zbase) {
  __shared__ bf16 tb[64][65];
  const int f32 = flagp[0];
  const int which = blockIdx.z + zbase;
  const void* src; bf16* dst; int N; int nbase;
  if      (which == 0) { src = Wq; dst = WQKVT; N = 2048; nbase = 0;    }
  else if (which == 1) { src = Wk; dst = WQKVT; N = 1024; nbase = 2048; }
  else if (which == 2) { src = Wv; dst = WQKVT; N = 1024; nbase = 3072; }
  else                 { src = Wo; dst = WOT;   N = 2048; nbase = 0;    }
  const int n0 = blockIdx.x * 64;
  if (n0 >= N) return;                 // uniform early-out, before any barrier
  const int k0 = blockIdx.y * 64;
  const int tx = threadIdx.x & 63, ty = threadIdx.x >> 6;
#pragma unroll
  for (int i = 0; i < 16; ++i) {
    int ks = ty + 4*i;
    tb[ks][tx] = (bf16)ld_elem(src, (size_t)(k0 + ks) * N + n0 + tx, f32);
  }
  __syncthreads();
#pragma unroll
  for (int i = 0; i < 16; ++i) {
    int ns = ty + 4*i;
    dst[(size_t)(nbase + n0 + ns) * 2048 + k0 + tx] = tb[tx][ns];
  }
}

__global__ void concat_bias(const void* __restrict__ bq, const void* __restrict__ bk,
                            const void* __restrict__ bv, bf16* __restrict__ bias,
                            const int* __restrict__ flagp) {
  const int f32 = flagp[0];
  int i = blockIdx.x * 256 + threadIdx.x;
  float v;
  if (i < 2048)      v = ld_elem(bq, i, f32);
  else if (i < 3072) v = ld_elem(bk, i - 2048, f32);
  else               v = ld_elem(bv, i - 3072, f32);
  bias[i] = (bf16)v;
}

// ---------------------------------------------------------------------------
// GEMM: C(MxN) = A(MxK) * BT(NxK)^T + bias, f32 accum. A,BT bf16.
// ROUND 11: R9 layout (0 bank conflicts) + two-barrier phases, but WITHOUT
// the lgkmcnt(0)/sched_barrier(0) order-pinning (m141 lesson): the compiler's
// own fine-grained lgkmcnt waits let each wave's first MFMA start as soon as
// its first operands land, overlapping LDS read-service of other waves with
// MFMA issue. Counted vmcnt fixed to exact unit-pair drains:
//   BM=256, holds at phase 1 & 3 ends, vmcnt(4):
//     entry ph0(t): outstanding [A1,B1](t) landed-check at ph1 end;
//     ph1-end: 8 outstanding -> drain A1,B1(t) (read ph2/ph3, issued 2 phases
//     earlier); ph3-end: drain A0,B0(t+1) (read ph0(t+1), issued 2-3 earlier).
//   BM=128: hold every phase, vmcnt(3) (drains the unit-pair read next phase,
//   issued 1 phase earlier). vmcnt never 0 in the loop.
// ---------------------------------------------------------------------------
template<int BM>
__global__ __launch_bounds__(512, 2) void gemm_big_kernel(
    const bf16* __restrict__ A, const bf16* __restrict__ BT,
    const bf16* __restrict__ bias, void* __restrict__ C, int N, int K,
    const int* __restrict__ flagp, int c_ext) {
  constexpr int RW = BM / 2;            // rows per wave
  constexpr int MH = RW / 64;           // m-half phases per k-half (2 or 1)
  constexpr int AL = BM / 128;          // A-unit loads per thread (2 or 1)
  constexpr int ACN = RW / 16;          // acc rows (8 or 4)
  constexpr int SLOT = BM * 64 + 16384; // elems per dbuf slot
  extern __shared__ bf16 lds[];
  const int cfl = c_ext ? flagp[0] : 0;
  const int t = threadIdx.x, lane = t & 63, wv = t >> 6;
  const int wm = wv >> 2, wn = wv & 3;
  const int quad = lane >> 4, l16 = lane & 15;
  const int m0 = blockIdx.y * BM, n0 = blockIdx.x * 256;
  const int NT = K >> 6;

  // per-lane read offset within a unit: row = base+l16 (base % 16 == 0),
  // chunk = quad. line = row>>1; slot = (row&1)*4+quad; slot' = slot^(line&7).
  const int soff = (l16 >> 1) * 64 + ((((l16 & 1) * 4 + quad) ^ (l16 >> 1)) * 8);

  f32x4 zero = {0.f, 0.f, 0.f, 0.f};
  f32x4 acc[ACN][4];
#pragma unroll
  for (int i = 0; i < ACN; ++i)
#pragma unroll
    for (int j = 0; j < 4; ++j) acc[i][j] = zero;

  auto vm_hold = [&]() {
    if constexpr (BM == 256) asm volatile("s_waitcnt vmcnt(4)" ::: "memory");
    else                     asm volatile("s_waitcnt vmcnt(3)" ::: "memory");
  };

  // stage unit (A or B) of k-half ks, tile kt -> slot kt&1. Source chunk is
  // pre-swizzled: LDS (line, slot) holds global (row=2*line+(g>>2), chunk=g&3)
  // where g = slot ^ (line&7).
  auto stageA = [&](int kt, int ks) {
    bf16* ub = lds + (size_t)(kt & 1) * SLOT + ks * (BM * 32);
#pragma unroll
    for (int q = 0; q < AL; ++q) {
      const int idx = q * 512 + t;
      const int line = idx >> 3;
      const int g = (idx & 7) ^ (line & 7);
      const int row = 2 * line + (g >> 2), ch = g & 3;
      async_copy16(ub + (size_t)(q * 512 + (t & ~63)) * 8,
                   A + (size_t)(m0 + row) * K + kt * 64 + ks * 32 + ch * 8);
    }
  };
  auto stageB = [&](int kt, int ks) {
    bf16* ub = lds + (size_t)(kt & 1) * SLOT + BM * 64 + ks * 8192;
#pragma unroll
    for (int q = 0; q < 2; ++q) {
      const int idx = q * 512 + t;
      const int line = idx >> 3;
      const int g = (idx & 7) ^ (line & 7);
      const int row = 2 * line + (g >> 2), ch = g & 3;
      async_copy16(ub + (size_t)(q * 512 + (t & ~63)) * 8,
                   BT + (size_t)(n0 + row) * K + kt * 64 + ks * 32 + ch * 8);
    }
  };

  // Prologue: tile0's 4 units; vmcnt(4) drains exactly Ak0,Bk0 (full units).
  stageA(0, 0); stageB(0, 0); stageA(0, 1); stageB(0, 1);
  vm_hold();
  __builtin_amdgcn_s_barrier();

  for (int jt = 0; jt < NT; ++jt) {
    const bf16* Abase = lds + (size_t)(jt & 1) * SLOT;
    const bf16* Bbase = Abase + BM * 64;
    const int nxt = (jt + 1 == NT) ? 0 : jt + 1;   // tail stages wrap (dummy, WAR-safe)
#pragma unroll
    for (int ks = 0; ks < 2; ++ks) {
      const bf16* Au = Abase + ks * (BM * 32);
      const bf16* Bu = Bbase + ks * 8192;
      bf16x8 bfr[4];
#pragma unroll
      for (int mh = 0; mh < MH; ++mh) {
        bf16x8 af[4];
#pragma unroll
        for (int mi = 0; mi < 4; ++mi)
          af[mi] = *(const bf16x8*)(Au + (wm * RW + mh * 64 + mi * 16) * 32 + soff);
        if (mh == 0) {
#pragma unroll
          for (int ni = 0; ni < 4; ++ni)
            bfr[ni] = *(const bf16x8*)(Bu + (wn * 64 + ni * 16) * 32 + soff);
        }
        // stage one unit of tile nxt (issue order Ak0,Bk0,Ak1,Bk1)
        if constexpr (BM == 256) {
          if (ks == 0) { if (mh == 0) stageA(nxt, 0); else stageB(nxt, 0); }
          else         { if (mh == 0) stageA(nxt, 1); else stageB(nxt, 1); }
        } else {
          stageA(nxt, ks); stageB(nxt, ks);
        }
        __builtin_amdgcn_s_barrier();                    // barrier 1: phase align
        __builtin_amdgcn_s_setprio(1);
#pragma unroll
        for (int mi = 0; mi < 4; ++mi)
#pragma unroll
          for (int ni = 0; ni < 4; ++ni)
            acc[mh * 4 + mi][ni] = __builtin_amdgcn_mfma_f32_16x16x32_bf16(
                af[mi], bfr[ni], acc[mh * 4 + mi][ni], 0, 0, 0);
        __builtin_amdgcn_s_setprio(0);
        // counted drain only at the end of each K-half (last phase of ks)
        if (mh == MH - 1) vm_hold();
        __builtin_amdgcn_s_barrier();                    // barrier 2: publish
      }
    }
  }
  // drain dummy tail DMAs before the block can exit
  asm volatile("s_waitcnt vmcnt(0)" ::: "memory");

  // Epilogue
#pragma unroll
  for (int ni = 0; ni < 4; ++ni) {
    const int col = n0 + wn * 64 + ni * 16 + l16;
    const float bvf = bias ? (float)bias[col] : 0.0f;
#pragma unroll
    for (int mi = 0; mi < ACN; ++mi) {
      const int rowb = m0 + wm * RW + mi * 16 + quad * 4;
#pragma unroll
      for (int r = 0; r < 4; ++r) {
        const float v = acc[mi][ni][r] + bvf;
        const size_t idx = (size_t)(rowb + r) * N + col;
        if (cfl) ((float*)C)[idx] = v;
        else     ((bf16*)C)[idx]  = (bf16)v;
      }
    }
  }
}

// ---------------------------------------------------------------------------
// RoPE in place on Q (cols 0..2047) and K (cols 2048..3071) of C1.
// ---------------------------------------------------------------------------
__global__ void rope_kernel(bf16* __restrict__ C1) {
  const int tx = threadIdx.x & 63, ty = threadIdx.x >> 6;
  const int row = blockIdx.x * 4 + ty;
  const int hh = blockIdx.y;
  const int col = (hh < kNH) ? hh * kD : kNH*kD + (hh - kNH) * kD;
  const int s = row & (kS - 1);
  const float freq = __expf(-(float)tx * (13.815510557964274f / 64.0f));
  const float ang = (float)s * freq;
  const float c = cosf(ang), sn = sinf(ang);
  const size_t base = (size_t)row * kNqkv + col;
  const float x1 = (float)C1[base + tx];
  const float x2 = (float)C1[base + 64 + tx];
  C1[base + tx]      = (bf16)(x1 * c - x2 * sn);
  C1[base + 64 + tx] = (bf16)(x2 * c + x1 * sn);
}

// ---------------------------------------------------------------------------
// V transpose: VT[b][kv][d][t] = C1[b*S+t][3072 + kv*128 + d]
// ---------------------------------------------------------------------------
__global__ void v_transpose(const bf16* __restrict__ C1, bf16* __restrict__ VT) {
  __shared__ bf16 tb[64][65];
  const int bkv = blockIdx.z;
  const int b = bkv >> 3, kv = bkv & 7;
  const int t0 = blockIdx.x * 64, d0 = blockIdx.y * 64;
  const int tx = threadIdx.x & 63, ty = threadIdx.x >> 6;
#pragma unroll
  for (int i = 0; i < 16; ++i) {
    int ts = ty + 4*i;
    tb[ts][tx] = C1[(size_t)(b*kS + t0 + ts) * kNqkv + 3072 + kv*kD + d0 + tx];
  }
  __syncthreads();
  const size_t obase = ((size_t)(b*kNKV + kv) * kD) * kS;
#pragma unroll
  for (int i = 0; i < 16; ++i) {
    int ds = ty + 4*i;
    VT[obase + (size_t)(d0 + ds) * kS + t0 + tx] = tb[tx][ds];
  }
}

// ---------------------------------------------------------------------------
// Flash attention, causal GQA, fixed-shift softmax.
// R10 (kept): R3-proven dual-compute causal pairing + setprio around MFMA.
// ---------------------------------------------------------------------------
__global__ __launch_bounds__(256) void attn_kernel(
    const bf16* __restrict__ C1, const bf16* __restrict__ VT, bf16* __restrict__ CTX) {
  constexpr int LDP = 72;
  __shared__ bf16 lds_k[2][64 * 128];
  __shared__ bf16 lds_v[2][128 * 64];
  __shared__ bf16 lds_p[4][16 * LDP];
  const int p = blockIdx.x, h = blockIdx.y, b = blockIdx.z;
  const int qtA = 31 - p;                     // big q-tile
  const int qtB = p;                          // small q-tile
  const int kvh = h >> 1;                     // G = 2
  const int t = threadIdx.x, lane = t & 63, wv = t >> 6;
  const int quad = lane >> 4, l16 = lane & 15;
  const float SC2 = 0.08838834764831845f * 1.4426950408889634f; // scale*log2(e)

  // Q fragments for both q-tiles (A-layout: m=lane&15, k=quad*8+j)
  bf16x8 qfA[4], qfB[4];
  {
    const size_t rowQA = (size_t)(b*kS + qtA*64 + wv*16 + l16) * kNqkv + h * kD;
    const size_t rowQB = (size_t)(b*kS + qtB*64 + wv*16 + l16) * kNqkv + h * kD;
#pragma unroll
    for (int c = 0; c < 4; ++c) {
      qfA[c] = *(const bf16x8*)(C1 + rowQA + c*32 + quad*8);
      qfB[c] = *(const bf16x8*)(C1 + rowQB + c*32 + quad*8);
    }
  }

  float lA[4] = {0,0,0,0}, lB[4] = {0,0,0,0};
  f32x4 oA[8], oB[8];
  f32x4 zero = {0.f, 0.f, 0.f, 0.f};
#pragma unroll
  for (int n = 0; n < 8; ++n) { oA[n] = zero; oB[n] = zero; }

  const int qrowA = qtA*64 + wv*16 + quad*4;
  const int qrowB = qtB*64 + wv*16 + quad*4;
  bf16* pw = &lds_p[wv][0];

  // staging geometry (per wave: 4 K regions + 4 V regions of 64 chunks)
  const size_t kbase = (size_t)b * kS * kNqkv + 2048 + kvh * kD;
  const size_t vbase = ((size_t)(b*kNKV + kvh) * kD) * kS;
  const int jv = (lane & 7) ^ ((lane >> 3) & 7);

  auto stage = [&](int buf, int k0) {
#pragma unroll
    for (int s2 = 0; s2 < 4; ++s2) {
      const int r = wv + s2 * 4;
      const int krow = r*4 + (lane >> 4);
      const int jk = (lane & 15) ^ (krow & 7);
      async_copy16(&lds_k[buf][r * 512], C1 + kbase + (size_t)(k0 + krow) * kNqkv + jk * 8);
      const int vrow = r*8 + (lane >> 3);
      async_copy16(&lds_v[buf][r * 512], VT + vbase + (size_t)vrow * kS + k0 + jv * 8);
    }
  };

  auto compute = [&](const bf16* kb_, const bf16* vb_, const bf16x8* qf,
                     f32x4* o_acc, float* l_acc, int qrow_base, int k0, bool diag) {
    // QK^T
    f32x4 sc4[4];
    __builtin_amdgcn_s_setprio(1);
#pragma unroll
    for (int g = 0; g < 4; ++g) {
      f32x4 s_acc = zero;
#pragma unroll
      for (int c = 0; c < 4; ++c) {
        bf16x8 kf = *(const bf16x8*)(kb_ + (g*16 + l16) * 128 + (((c*4 + quad) ^ (l16 & 7)) * 8));
        s_acc = __builtin_amdgcn_mfma_f32_16x16x32_bf16(qf[c], kf, s_acc, 0, 0, 0);
      }
      sc4[g] = s_acc;
    }
    __builtin_amdgcn_s_setprio(0);
    // fixed-shift exponential + causal mask (diagonal tile only) + P write
#pragma unroll
    for (int g = 0; g < 4; ++g) {
#pragma unroll
      for (int r = 0; r < 4; ++r) {
        float pv = __builtin_amdgcn_exp2f(fmaf(sc4[g][r], SC2, -24.f));
        if (diag && (k0 + g*16 + l16 > qrow_base + r)) pv = 0.f;
        l_acc[r] += pv;
        pw[(quad*4 + r) * LDP + g*16 + l16] = (bf16)pv;
      }
    }
    __builtin_amdgcn_wave_barrier();   // DS pipe in-order per wave: write->read
    // PV
    __builtin_amdgcn_s_setprio(1);
#pragma unroll
    for (int kk = 0; kk < 2; ++kk) {
      bf16x8 pf = *(const bf16x8*)(pw + l16 * LDP + kk*32 + quad*8);
#pragma unroll
      for (int n = 0; n < 8; ++n) {
        bf16x8 vf = *(const bf16x8*)(vb_ + (n*16 + l16) * 64 + (((kk*4 + quad) ^ (l16 & 7)) * 8));
        o_acc[n] = __builtin_amdgcn_mfma_f32_16x16x32_bf16(pf, vf, o_acc[n], 0, 0, 0);
      }
    }
    __builtin_amdgcn_s_setprio(0);
    __builtin_amdgcn_wave_barrier();   // later P writes stay after these reads
  };

  stage(0, 0);                         // prologue: key-tile 0 -> buf 0
  for (int kt = 0; kt <= qtA; ++kt) {
    const int cur = kt & 1;
    __syncthreads();                   // drain buf[cur] copies; all waves done with buf[1-cur]
    if (kt + 1 <= qtA) stage(1 - cur, (kt + 1) * 64);
    const int k0 = kt * 64;
    compute(&lds_k[cur][0], &lds_v[cur][0], qfA, oA, lA, qrowA, k0, kt == qtA);
    if (kt <= qtB)
      compute(&lds_k[cur][0], &lds_v[cur][0], qfB, oB, lB, qrowB, k0, kt == qtB);
  }

  // epilogue: l reduction across the 16 key-lanes, then normalize + store
  float invA[4], invB[4];
#pragma unroll
  for (int r = 0; r < 4; ++r) {
    float la = lA[r], lb = lB[r];
    la += __shfl_xor(la, 1); lb += __shfl_xor(lb, 1);
    la += __shfl_xor(la, 2); lb += __shfl_xor(lb, 2);
    la += __shfl_xor(la, 4); lb += __shfl_xor(lb, 4);
    la += __shfl_xor(la, 8); lb += __shfl_xor(lb, 8);
    invA[r] = 1.0f / la;     invB[r] = 1.0f / lb;
  }
#pragma unroll
  for (int n = 0; n < 8; ++n) {
#pragma unroll
    for (int r = 0; r < 4; ++r) {
      CTX[(size_t)(b*kS + qrowA + r) * (kNH*kD) + h*kD + n*16 + l16] = (bf16)(oA[n][r] * invA[r]);
      CTX[(size_t)(b*kS + qrowB + r) * (kNH*kD) + h*kD + n*16 + l16] = (bf16)(oB[n][r] * invB[r]);
    }
  }
}

// ---------------------------------------------------------------------------
// Workspace layout (liveness-overlapped; peak ~75.5 MB):
//   C1    [0,32M)   gemm1->attn      WOT [0,8M) after attn
//   WQKVT [32M,48M) start->gemm1     VT [32M,40M) v_transpose->attn
//   CTX   [40M,56M) attn->gemm2
//   HSB   [56M,72M) convert->gemm1
//   BIAS  [72M,+8K), FLAG [72M+8K)
// ---------------------------------------------------------------------------
extern "C" void kernel_launch(void* const* d_in, const int* in_sizes, int n_in,
                              void* d_out, int out_size, void* d_ws, size_t ws_size,
                              hipStream_t stream) {
  const void* hs = d_in[0];
  const void* Wq = d_in[1];
  const void* bq = d_in[2];
  const void* Wk = d_in[3];
  const void* bk = d_in[4];
  const void* Wv = d_in[5];
  const void* bv = d_in[6];
  const void* Wo = d_in[7];

  char* ws = (char*)d_ws;
  bf16* C1    = (bf16*)(ws + 0);
  bf16* WOT   = (bf16*)(ws + 0);
  bf16* WQKVT = (bf16*)(ws + 33554432);
  bf16* VT    = (bf16*)(ws + 33554432);
  bf16* CTX   = (bf16*)(ws + 41943040);
  bf16* HSB   = (bf16*)(ws + 58720256);
  bf16* BIAS  = (bf16*)(ws + 75497472);
  int*  FLAG  = (int*) (ws + 75505664);

  // dynamic LDS above the 64 KiB default cap
  (void)hipFuncSetAttribute((const void*)gemm_big_kernel<256>,
                            hipFuncAttributeMaxDynamicSharedMemorySize, 131072);
  (void)hipFuncSetAttribute((const void*)gemm_big_kernel<128>,
                            hipFuncAttributeMaxDynamicSharedMemorySize, 98304);

  detect_dtype<<<1, 256, 0, stream>>>((const unsigned short*)hs, FLAG);
  convert_hs<<<4096, 256, 0, stream>>>(hs, HSB, FLAG);
  transpose_weights<<<dim3(32, 32, 3), 256, 0, stream>>>(Wq, Wk, Wv, Wo, WQKVT, WOT, FLAG, 0);
  concat_bias<<<16, 256, 0, stream>>>(bq, bk, bv, BIAS, FLAG);
  gemm_big_kernel<256><<<dim3(16, 16), 512, 131072, stream>>>(HSB, WQKVT, BIAS, C1, 4096, 2048, FLAG, 0);
  rope_kernel<<<dim3(1024, 24), 256, 0, stream>>>(C1);
  v_transpose<<<dim3(32, 2, 16), 256, 0, stream>>>(C1, VT);
  attn_kernel<<<dim3(16, 16, 2), 256, 0, stream>>>(C1, VT, CTX);
  transpose_weights<<<dim3(32, 32, 1), 256, 0, stream>>>(Wq, Wk, Wv, Wo, WQKVT, WOT, FLAG, 3);
  gemm_big_kernel<128><<<dim3(8, 32), 512, 98304, stream>>>(CTX, WOT, nullptr, d_out, 2048, 2048, FLAG, 1);
}

// Round 7
// 356.448 us; speedup vs baseline: 1.0246x; 1.0246x over previous
//
#include <hip/hip_runtime.h>

typedef __bf16 bf16;
typedef __attribute__((ext_vector_type(8))) __bf16 bf16x8;
typedef __attribute__((ext_vector_type(4))) float f32x4;

// Problem constants
constexpr int kS   = 2048;
constexpr int kNH  = 16;
constexpr int kNKV = 8;
constexpr int kD   = 128;
constexpr int kNqkv = 4096;   // NH*D + 2*NKV*D

// ---------------------------------------------------------------------------
// async global->LDS, 16 B per lane. LDS dest is wave-uniform base + lane*16.
// ---------------------------------------------------------------------------
__device__ __forceinline__ void async_copy16(void* lds_base_uniform, const void* g) {
  __builtin_amdgcn_global_load_lds(
      (const __attribute__((address_space(1))) void*)g,
      (__attribute__((address_space(3))) void*)lds_base_uniform, 16, 0, 0);
}

// ---------------------------------------------------------------------------
// Dtype detector: flag=1 if inputs are float32, 0 if bf16 (verified R2: f32).
// ---------------------------------------------------------------------------
__global__ void detect_dtype(const unsigned short* __restrict__ hs, int* __restrict__ flag) {
  __shared__ int cnt;
  if (threadIdx.x == 0) cnt = 0;
  __syncthreads();
  int local = 0;
  for (int i = threadIdx.x; i < 8192; i += 256) {
    int e = (hs[i] >> 7) & 0xFF;
    local += (e >= 0x85) ? 1 : 0;
  }
  atomicAdd(&cnt, local);
  __syncthreads();
  if (threadIdx.x == 0) flag[0] = (cnt > 256) ? 1 : 0;
}

__device__ __forceinline__ float ld_elem(const void* p, size_t i, int f32) {
  return f32 ? ((const float*)p)[i] : (float)((const bf16*)p)[i];
}

__device__ __forceinline__ bf16x8 load8(const void* base, size_t eoff, int f32) {
  if (f32) {
    const float* p = (const float*)base + eoff;
    f32x4 a = *(const f32x4*)p;
    f32x4 b = *(const f32x4*)(p + 4);
    bf16x8 r;
    r[0]=(bf16)a[0]; r[1]=(bf16)a[1]; r[2]=(bf16)a[2]; r[3]=(bf16)a[3];
    r[4]=(bf16)b[0]; r[5]=(bf16)b[1]; r[6]=(bf16)b[2]; r[7]=(bf16)b[3];
    return r;
  }
  return *(const bf16x8*)((const bf16*)base + eoff);
}

// ---------------------------------------------------------------------------
// hs (f32 or bf16 per flag) -> bf16, so gemm1 can use the pure async path.
// ---------------------------------------------------------------------------
__global__ void convert_hs(const void* __restrict__ hs, bf16* __restrict__ out,
                           const int* __restrict__ flagp) {
  const int f32 = flagp[0];
  const size_t i = ((size_t)blockIdx.x * 256 + threadIdx.x) * 8;
  *(bf16x8*)(out + i) = load8(hs, i, f32);
}

// ---------------------------------------------------------------------------
// Weight transpose: W (K x N) row-major -> WT (N x K) row-major, K = 2048.
// ---------------------------------------------------------------------------
__global__ void transpose_weights(const void* __restrict__ Wq, const void* __restrict__ Wk,
                                  const void* __restrict__ Wv, const void* __restrict__ Wo,
                                  bf16* __restrict__ WQKVT, bf16* __restrict__ WOT,
                                  const int* __restrict__ flagp, int zbase) {
  __shared__ bf16 tb[64][65];
  const int f32 = flagp[0];
  const int which = blockIdx.z + zbase;
  const void* src; bf16* dst; int N; int nbase;
  if      (which == 0) { src = Wq; dst = WQKVT; N = 2048; nbase = 0;    }
  else if (which == 1) { src = Wk; dst = WQKVT; N = 1024; nbase = 2048; }
  else if (which == 2) { src = Wv; dst = WQKVT; N = 1024; nbase = 3072; }
  else                 { src = Wo; dst = WOT;   N = 2048; nbase = 0;    }
  const int n0 = blockIdx.x * 64;
  if (n0 >= N) return;                 // uniform early-out, before any barrier
  const int k0 = blockIdx.y * 64;
  const int tx = threadIdx.x & 63, ty = threadIdx.x >> 6;
#pragma unroll
  for (int i = 0; i < 16; ++i) {
    int ks = ty + 4*i;
    tb[ks][tx] = (bf16)ld_elem(src, (size_t)(k0 + ks) * N + n0 + tx, f32);
  }
  __syncthreads();
#pragma unroll
  for (int i = 0; i < 16; ++i) {
    int ns = ty + 4*i;
    dst[(size_t)(nbase + n0 + ns) * 2048 + k0 + tx] = tb[tx][ns];
  }
}

__global__ void concat_bias(const void* __restrict__ bq, const void* __restrict__ bk,
                            const void* __restrict__ bv, bf16* __restrict__ bias,
                            const int* __restrict__ flagp) {
  const int f32 = flagp[0];
  int i = blockIdx.x * 256 + threadIdx.x;
  float v;
  if (i < 2048)      v = ld_elem(bq, i, f32);
  else if (i < 3072) v = ld_elem(bk, i - 2048, f32);
  else               v = ld_elem(bv, i - 3072, f32);
  bias[i] = (bf16)v;
}

// ---------------------------------------------------------------------------
// GEMM: C(MxN) = A(MxK) * BT(NxK)^T + bias, f32 accum. A,BT bf16.
// ROUND 12: R9 layout (0 bank conflicts) but TWO phases per K-tile (one per
// K-half) instead of four -- halves the barrier-round count, which R5/R6
// showed to be a ~600cy/phase fixed tax. Per phase (both BM):
//   { ACN A-frag + 4 B-frag ds_reads || stage A+B units of tile t+1, same
//     k-half } -> barrier -> setprio(1) ACNx4 MFMA setprio(0) -> counted
//     vmcnt hold -> barrier.
// vmcnt ledger (copies/phase P = BM/128 + 2; hold = P):
//   prologue 2P issued, hold P -> drains Ak0,Bk0 of tile0.
//   phase(t,ks): issues P; outstanding 2P; hold P -> drains the unit-pair
//   read in the NEXT phase, issued one full phase (~1900cy) earlier.
//   Never 0 in-loop. WAR: staged slot's reads finished before prior barrier.
// VGPR headroom is free (LDS caps CU at 8 waves): af[ACN]+bfr[4]+acc ~ 210.
// ---------------------------------------------------------------------------
template<int BM>
__global__ __launch_bounds__(512, 2) void gemm_big_kernel(
    const bf16* __restrict__ A, const bf16* __restrict__ BT,
    const bf16* __restrict__ bias, void* __restrict__ C, int N, int K,
    const int* __restrict__ flagp, int c_ext) {
  constexpr int RW = BM / 2;            // rows per wave
  constexpr int AL = BM / 128;          // A-unit loads per thread (2 or 1)
  constexpr int ACN = RW / 16;          // acc rows / A-frags per phase (8 or 4)
  constexpr int SLOT = BM * 64 + 16384; // elems per dbuf slot
  extern __shared__ bf16 lds[];
  const int cfl = c_ext ? flagp[0] : 0;
  const int t = threadIdx.x, lane = t & 63, wv = t >> 6;
  const int wm = wv >> 2, wn = wv & 3;
  const int quad = lane >> 4, l16 = lane & 15;
  const int m0 = blockIdx.y * BM, n0 = blockIdx.x * 256;
  const int NT = K >> 6;

  // per-lane read offset within a unit: row = base+l16 (base % 16 == 0),
  // chunk = quad. line = row>>1; slot = (row&1)*4+quad; slot' = slot^(line&7).
  const int soff = (l16 >> 1) * 64 + ((((l16 & 1) * 4 + quad) ^ (l16 >> 1)) * 8);

  f32x4 zero = {0.f, 0.f, 0.f, 0.f};
  f32x4 acc[ACN][4];
#pragma unroll
  for (int i = 0; i < ACN; ++i)
#pragma unroll
    for (int j = 0; j < 4; ++j) acc[i][j] = zero;

  auto vm_hold = [&]() {
    if constexpr (BM == 256) asm volatile("s_waitcnt vmcnt(4)" ::: "memory");
    else                     asm volatile("s_waitcnt vmcnt(3)" ::: "memory");
  };

  // stage unit (A or B) of k-half ks, tile kt -> slot kt&1. Source chunk is
  // pre-swizzled: LDS (line, slot) holds global (row=2*line+(g>>2), chunk=g&3)
  // where g = slot ^ (line&7).
  auto stageA = [&](int kt, int ks) {
    bf16* ub = lds + (size_t)(kt & 1) * SLOT + ks * (BM * 32);
#pragma unroll
    for (int q = 0; q < AL; ++q) {
      const int idx = q * 512 + t;
      const int line = idx >> 3;
      const int g = (idx & 7) ^ (line & 7);
      const int row = 2 * line + (g >> 2), ch = g & 3;
      async_copy16(ub + (size_t)(q * 512 + (t & ~63)) * 8,
                   A + (size_t)(m0 + row) * K + kt * 64 + ks * 32 + ch * 8);
    }
  };
  auto stageB = [&](int kt, int ks) {
    bf16* ub = lds + (size_t)(kt & 1) * SLOT + BM * 64 + ks * 8192;
#pragma unroll
    for (int q = 0; q < 2; ++q) {
      const int idx = q * 512 + t;
      const int line = idx >> 3;
      const int g = (idx & 7) ^ (line & 7);
      const int row = 2 * line + (g >> 2), ch = g & 3;
      async_copy16(ub + (size_t)(q * 512 + (t & ~63)) * 8,
                   BT + (size_t)(n0 + row) * K + kt * 64 + ks * 32 + ch * 8);
    }
  };

  // Prologue: tile0's 4 units; hold drains exactly Ak0,Bk0 (full units).
  stageA(0, 0); stageB(0, 0); stageA(0, 1); stageB(0, 1);
  vm_hold();
  __builtin_amdgcn_s_barrier();

  for (int jt = 0; jt < NT; ++jt) {
    const bf16* Abase = lds + (size_t)(jt & 1) * SLOT;
    const bf16* Bbase = Abase + BM * 64;
    const int nxt = (jt + 1 == NT) ? 0 : jt + 1;   // tail stages wrap (dummy, WAR-safe)
#pragma unroll
    for (int ks = 0; ks < 2; ++ks) {
      const bf16* Au = Abase + ks * (BM * 32);
      const bf16* Bu = Bbase + ks * 8192;
      bf16x8 af[ACN], bfr[4];
#pragma unroll
      for (int mi = 0; mi < ACN; ++mi)
        af[mi] = *(const bf16x8*)(Au + (wm * RW + mi * 16) * 32 + soff);
#pragma unroll
      for (int ni = 0; ni < 4; ++ni)
        bfr[ni] = *(const bf16x8*)(Bu + (wn * 64 + ni * 16) * 32 + soff);

      // stage the same k-half units of tile nxt
      stageA(nxt, ks); stageB(nxt, ks);

      __builtin_amdgcn_s_barrier();                    // barrier 1: phase align
      __builtin_amdgcn_s_setprio(1);
#pragma unroll
      for (int mi = 0; mi < ACN; ++mi)
#pragma unroll
        for (int ni = 0; ni < 4; ++ni)
          acc[mi][ni] = __builtin_amdgcn_mfma_f32_16x16x32_bf16(
              af[mi], bfr[ni], acc[mi][ni], 0, 0, 0);
      __builtin_amdgcn_s_setprio(0);
      vm_hold();                                       // counted drain (never 0)
      __builtin_amdgcn_s_barrier();                    // barrier 2: publish
    }
  }
  // drain dummy tail DMAs before the block can exit
  asm volatile("s_waitcnt vmcnt(0)" ::: "memory");

  // Epilogue
#pragma unroll
  for (int ni = 0; ni < 4; ++ni) {
    const int col = n0 + wn * 64 + ni * 16 + l16;
    const float bvf = bias ? (float)bias[col] : 0.0f;
#pragma unroll
    for (int mi = 0; mi < ACN; ++mi) {
      const int rowb = m0 + wm * RW + mi * 16 + quad * 4;
#pragma unroll
      for (int r = 0; r < 4; ++r) {
        const float v = acc[mi][ni][r] + bvf;
        const size_t idx = (size_t)(rowb + r) * N + col;
        if (cfl) ((float*)C)[idx] = v;
        else     ((bf16*)C)[idx]  = (bf16)v;
      }
    }
  }
}

// ---------------------------------------------------------------------------
// RoPE in place on Q (cols 0..2047) and K (cols 2048..3071) of C1.
// ROUND 12: hardware v_sin/v_cos (revolutions + floor reduction) instead of
// libm cosf/sinf -- removes the double accurate argument-reduction (VALU
// sink). |err| ~1e-4 rad-equivalent, far below bf16 rounding.
// ---------------------------------------------------------------------------
__global__ void rope_kernel(bf16* __restrict__ C1) {
  const int tx = threadIdx.x & 63, ty = threadIdx.x >> 6;
  const int row = blockIdx.x * 4 + ty;
  const int hh = blockIdx.y;
  const int col = (hh < kNH) ? hh * kD : kNH*kD + (hh - kNH) * kD;
  const int s = row & (kS - 1);
  const float freq = __expf(-(float)tx * (13.815510557964274f / 64.0f));
  const float rev0 = (float)s * freq * 0.15915494309189535f;   // angle in revolutions
  const float rev = rev0 - floorf(rev0);                        // reduce to [0,1)
  const float c  = __builtin_amdgcn_cosf(rev);
  const float sn = __builtin_amdgcn_sinf(rev);
  const size_t base = (size_t)row * kNqkv + col;
  const float x1 = (float)C1[base + tx];
  const float x2 = (float)C1[base + 64 + tx];
  C1[base + tx]      = (bf16)(x1 * c - x2 * sn);
  C1[base + 64 + tx] = (bf16)(x2 * c + x1 * sn);
}

// ---------------------------------------------------------------------------
// V transpose: VT[b][kv][d][t] = C1[b*S+t][3072 + kv*128 + d]
// ---------------------------------------------------------------------------
__global__ void v_transpose(const bf16* __restrict__ C1, bf16* __restrict__ VT) {
  __shared__ bf16 tb[64][65];
  const int bkv = blockIdx.z;
  const int b = bkv >> 3, kv = bkv & 7;
  const int t0 = blockIdx.x * 64, d0 = blockIdx.y * 64;
  const int tx = threadIdx.x & 63, ty = threadIdx.x >> 6;
#pragma unroll
  for (int i = 0; i < 16; ++i) {
    int ts = ty + 4*i;
    tb[ts][tx] = C1[(size_t)(b*kS + t0 + ts) * kNqkv + 3072 + kv*kD + d0 + tx];
  }
  __syncthreads();
  const size_t obase = ((size_t)(b*kNKV + kv) * kD) * kS;
#pragma unroll
  for (int i = 0; i < 16; ++i) {
    int ds = ty + 4*i;
    VT[obase + (size_t)(d0 + ds) * kS + t0 + tx] = tb[tx][ds];
  }
}

// ---------------------------------------------------------------------------
// Flash attention, causal GQA, fixed-shift softmax.
// R10 (kept): R3-proven dual-compute causal pairing + setprio around MFMA.
// ---------------------------------------------------------------------------
__global__ __launch_bounds__(256) void attn_kernel(
    const bf16* __restrict__ C1, const bf16* __restrict__ VT, bf16* __restrict__ CTX) {
  constexpr int LDP = 72;
  __shared__ bf16 lds_k[2][64 * 128];
  __shared__ bf16 lds_v[2][128 * 64];
  __shared__ bf16 lds_p[4][16 * LDP];
  const int p = blockIdx.x, h = blockIdx.y, b = blockIdx.z;
  const int qtA = 31 - p;                     // big q-tile
  const int qtB = p;                          // small q-tile
  const int kvh = h >> 1;                     // G = 2
  const int t = threadIdx.x, lane = t & 63, wv = t >> 6;
  const int quad = lane >> 4, l16 = lane & 15;
  const float SC2 = 0.08838834764831845f * 1.4426950408889634f; // scale*log2(e)

  // Q fragments for both q-tiles (A-layout: m=lane&15, k=quad*8+j)
  bf16x8 qfA[4], qfB[4];
  {
    const size_t rowQA = (size_t)(b*kS + qtA*64 + wv*16 + l16) * kNqkv + h * kD;
    const size_t rowQB = (size_t)(b*kS + qtB*64 + wv*16 + l16) * kNqkv + h * kD;
#pragma unroll
    for (int c = 0; c < 4; ++c) {
      qfA[c] = *(const bf16x8*)(C1 + rowQA + c*32 + quad*8);
      qfB[c] = *(const bf16x8*)(C1 + rowQB + c*32 + quad*8);
    }
  }

  float lA[4] = {0,0,0,0}, lB[4] = {0,0,0,0};
  f32x4 oA[8], oB[8];
  f32x4 zero = {0.f, 0.f, 0.f, 0.f};
#pragma unroll
  for (int n = 0; n < 8; ++n) { oA[n] = zero; oB[n] = zero; }

  const int qrowA = qtA*64 + wv*16 + quad*4;
  const int qrowB = qtB*64 + wv*16 + quad*4;
  bf16* pw = &lds_p[wv][0];

  // staging geometry (per wave: 4 K regions + 4 V regions of 64 chunks)
  const size_t kbase = (size_t)b * kS * kNqkv + 2048 + kvh * kD;
  const size_t vbase = ((size_t)(b*kNKV + kvh) * kD) * kS;
  const int jv = (lane & 7) ^ ((lane >> 3) & 7);

  auto stage = [&](int buf, int k0) {
#pragma unroll
    for (int s2 = 0; s2 < 4; ++s2) {
      const int r = wv + s2 * 4;
      const int krow = r*4 + (lane >> 4);
      const int jk = (lane & 15) ^ (krow & 7);
      async_copy16(&lds_k[buf][r * 512], C1 + kbase + (size_t)(k0 + krow) * kNqkv + jk * 8);
      const int vrow = r*8 + (lane >> 3);
      async_copy16(&lds_v[buf][r * 512], VT + vbase + (size_t)vrow * kS + k0 + jv * 8);
    }
  };

  auto compute = [&](const bf16* kb_, const bf16* vb_, const bf16x8* qf,
                     f32x4* o_acc, float* l_acc, int qrow_base, int k0, bool diag) {
    // QK^T
    f32x4 sc4[4];
    __builtin_amdgcn_s_setprio(1);
#pragma unroll
    for (int g = 0; g < 4; ++g) {
      f32x4 s_acc = zero;
#pragma unroll
      for (int c = 0; c < 4; ++c) {
        bf16x8 kf = *(const bf16x8*)(kb_ + (g*16 + l16) * 128 + (((c*4 + quad) ^ (l16 & 7)) * 8));
        s_acc = __builtin_amdgcn_mfma_f32_16x16x32_bf16(qf[c], kf, s_acc, 0, 0, 0);
      }
      sc4[g] = s_acc;
    }
    __builtin_amdgcn_s_setprio(0);
    // fixed-shift exponential + causal mask (diagonal tile only) + P write
#pragma unroll
    for (int g = 0; g < 4; ++g) {
#pragma unroll
      for (int r = 0; r < 4; ++r) {
        float pv = __builtin_amdgcn_exp2f(fmaf(sc4[g][r], SC2, -24.f));
        if (diag && (k0 + g*16 + l16 > qrow_base + r)) pv = 0.f;
        l_acc[r] += pv;
        pw[(quad*4 + r) * LDP + g*16 + l16] = (bf16)pv;
      }
    }
    __builtin_amdgcn_wave_barrier();   // DS pipe in-order per wave: write->read
    // PV
    __builtin_amdgcn_s_setprio(1);
#pragma unroll
    for (int kk = 0; kk < 2; ++kk) {
      bf16x8 pf = *(const bf16x8*)(pw + l16 * LDP + kk*32 + quad*8);
#pragma unroll
      for (int n = 0; n < 8; ++n) {
        bf16x8 vf = *(const bf16x8*)(vb_ + (n*16 + l16) * 64 + (((kk*4 + quad) ^ (l16 & 7)) * 8));
        o_acc[n] = __builtin_amdgcn_mfma_f32_16x16x32_bf16(pf, vf, o_acc[n], 0, 0, 0);
      }
    }
    __builtin_amdgcn_s_setprio(0);
    __builtin_amdgcn_wave_barrier();   // later P writes stay after these reads
  };

  stage(0, 0);                         // prologue: key-tile 0 -> buf 0
  for (int kt = 0; kt <= qtA; ++kt) {
    const int cur = kt & 1;
    __syncthreads();                   // drain buf[cur] copies; all waves done with buf[1-cur]
    if (kt + 1 <= qtA) stage(1 - cur, (kt + 1) * 64);
    const int k0 = kt * 64;
    compute(&lds_k[cur][0], &lds_v[cur][0], qfA, oA, lA, qrowA, k0, kt == qtA);
    if (kt <= qtB)
      compute(&lds_k[cur][0], &lds_v[cur][0], qfB, oB, lB, qrowB, k0, kt == qtB);
  }

  // epilogue: l reduction across the 16 key-lanes, then normalize + store
  float invA[4], invB[4];
#pragma unroll
  for (int r = 0; r < 4; ++r) {
    float la = lA[r], lb = lB[r];
    la += __shfl_xor(la, 1); lb += __shfl_xor(lb, 1);
    la += __shfl_xor(la, 2); lb += __shfl_xor(lb, 2);
    la += __shfl_xor(la, 4); lb += __shfl_xor(lb, 4);
    la += __shfl_xor(la, 8); lb += __shfl_xor(lb, 8);
    invA[r] = 1.0f / la;     invB[r] = 1.0f / lb;
  }
#pragma unroll
  for (int n = 0; n < 8; ++n) {
#pragma unroll
    for (int r = 0; r < 4; ++r) {
      CTX[(size_t)(b*kS + qrowA + r) * (kNH*kD) + h*kD + n*16 + l16] = (bf16)(oA[n][r] * invA[r]);
      CTX[(size_t)(b*kS + qrowB + r) * (kNH*kD) + h*kD + n*16 + l16] = (bf16)(oB[n][r] * invB[r]);
    }
  }
}

// ---------------------------------------------------------------------------
// Workspace layout (liveness-overlapped; peak ~75.5 MB):
//   C1    [0,32M)   gemm1->attn      WOT [0,8M) after attn
//   WQKVT [32M,48M) start->gemm1     VT [32M,40M) v_transpose->attn
//   CTX   [40M,56M) attn->gemm2
//   HSB   [56M,72M) convert->gemm1
//   BIAS  [72M,+8K), FLAG [72M+8K)
// ---------------------------------------------------------------------------
extern "C" void kernel_launch(void* const* d_in, const int* in_sizes, int n_in,
                              void* d_out, int out_size, void* d_ws, size_t ws_size,
                              hipStream_t stream) {
  const void* hs = d_in[0];
  const void* Wq = d_in[1];
  const void* bq = d_in[2];
  const void* Wk = d_in[3];
  const void* bk = d_in[4];
  const void* Wv = d_in[5];
  const void* bv = d_in[6];
  const void* Wo = d_in[7];

  char* ws = (char*)d_ws;
  bf16* C1    = (bf16*)(ws + 0);
  bf16* WOT   = (bf16*)(ws + 0);
  bf16* WQKVT = (bf16*)(ws + 33554432);
  bf16* VT    = (bf16*)(ws + 33554432);
  bf16* CTX   = (bf16*)(ws + 41943040);
  bf16* HSB   = (bf16*)(ws + 58720256);
  bf16* BIAS  = (bf16*)(ws + 75497472);
  int*  FLAG  = (int*) (ws + 75505664);

  // dynamic LDS above the 64 KiB default cap
  (void)hipFuncSetAttribute((const void*)gemm_big_kernel<256>,
                            hipFuncAttributeMaxDynamicSharedMemorySize, 131072);
  (void)hipFuncSetAttribute((const void*)gemm_big_kernel<128>,
                            hipFuncAttributeMaxDynamicSharedMemorySize, 98304);

  detect_dtype<<<1, 256, 0, stream>>>((const unsigned short*)hs, FLAG);
  convert_hs<<<4096, 256, 0, stream>>>(hs, HSB, FLAG);
  transpose_weights<<<dim3(32, 32, 3), 256, 0, stream>>>(Wq, Wk, Wv, Wo, WQKVT, WOT, FLAG, 0);
  concat_bias<<<16, 256, 0, stream>>>(bq, bk, bv, BIAS, FLAG);
  gemm_big_kernel<256><<<dim3(16, 16), 512, 131072, stream>>>(HSB, WQKVT, BIAS, C1, 4096, 2048, FLAG, 0);
  rope_kernel<<<dim3(1024, 24), 256, 0, stream>>>(C1);
  v_transpose<<<dim3(32, 2, 16), 256, 0, stream>>>(C1, VT);
  attn_kernel<<<dim3(16, 16, 2), 256, 0, stream>>>(C1, VT, CTX);
  transpose_weights<<<dim3(32, 32, 1), 256, 0, stream>>>(Wq, Wk, Wv, Wo, WQKVT, WOT, FLAG, 3);
  gemm_big_kernel<128><<<dim3(8, 32), 512, 98304, stream>>>(CTX, WOT, nullptr, d_out, 2048, 2048, FLAG, 1);
}